// Round 2
// baseline (551.465 us; speedup 1.0000x reference)
//
#include <hip/hip_runtime.h>
#include <hip/hip_bf16.h>
#include <stdint.h>

// SSL hashed-sparse linear: out[M,N] = x[M,K] @ w_full[N,K]^T + bias
// w_full[n,k] = weight[n, h(n/32, k/32)*32 + k%32],
// h = ((kb*r0 + nb*r1 + r2) ^ r3) % num_red_kb   (uint32 arithmetic)
//
// ROUND-1 FINDING: inputs/output are fp32 (round-0 bf16 read gave NaN —
// only possible if the ushorts were fp32 mantissa halves). Compute in bf16
// MFMA (2% threshold allows it); staging converts fp32->bf16 via VGPRs.
// 128x128x32 tile, 256 thr / 4 waves (2x2), 4x4 frags mfma_f32_16x16x32_bf16.
// Register ping-pong prefetch: next K-step's float4 loads stay in flight
// across the MFMA phase (no vmcnt(0)-at-barrier drain for register loads).

typedef __bf16 bf16x4_t __attribute__((ext_vector_type(4)));
typedef __bf16 bf16x8_t __attribute__((ext_vector_type(8)));
typedef float f32x4 __attribute__((ext_vector_type(4)));

#define BM 128
#define BN 128
#define BK 32

__global__ __launch_bounds__(256, 1) void ssl_gemm(
    const float* __restrict__ X,       // [M,K]
    const float* __restrict__ W,       // [N,redK]
    const float* __restrict__ Bias,    // [N]
    const int* __restrict__ RN,        // [4]
    float* __restrict__ Out,           // [M,N]
    int M, int N, int K, int redK, uint32_t numRedKb, int mTiles) {
  __shared__ __align__(16) __bf16 As[BM * BK];  // 128x32 bf16, 64B rows
  __shared__ __align__(16) __bf16 Bs[BN * BK];

  const uint32_t r0 = (uint32_t)RN[0], r1 = (uint32_t)RN[1];
  const uint32_t r2 = (uint32_t)RN[2], r3 = (uint32_t)RN[3];
  const uint32_t redMask = numRedKb - 1u;
  const bool pow2 = (numRedKb & (numRedKb - 1u)) == 0u;

  const int id = blockIdx.x;
  // blocks sharing an m-tile (ids m, m+64, m+128, m+192) have equal id%8
  // -> same XCD -> x rows fetched from HBM ~once, re-reads hit L2.
  const int mTile = id % mTiles;
  const int nTile = id / mTiles;

  const int tid = threadIdx.x;
  const int wave = tid >> 6;
  const int lane = tid & 63;
  const int wm = wave >> 1, wn = wave & 1;  // 2x2 wave grid, each 64x64

  // ---- staging map: thread covers rows {i*32+lRow} (i=0..3), cols lCol..+3
  const int lRow = tid >> 3;        // 0..31
  const int lCol = (tid & 7) << 2;  // 0,4,..,28 (fp32/bf16 elems)
  const float* aBase = X + (size_t)(mTile * BM + lRow) * K + lCol;
  const float* bBase = W + (size_t)(nTile * BN + lRow) * redK + lCol;

  auto loadA = [&](int kb, f32x4* r) {
    const float* p = aBase + (size_t)kb * BK;
#pragma unroll
    for (int i = 0; i < 4; ++i)
      r[i] = *(const f32x4*)(p + (size_t)(i * 32) * K);
  };
  auto loadB = [&](int kb, f32x4* r) {
    const uint32_t kk = (uint32_t)kb * r0 + r2;
#pragma unroll
    for (int i = 0; i < 4; ++i) {  // n-block of rows i*32..i*32+31 is nb
      const uint32_t nb = (uint32_t)(nTile * (BN / 32) + i);
      const uint32_t hv = (kk + nb * r1) ^ r3;
      const uint32_t h = pow2 ? (hv & redMask) : (hv % numRedKb);
      r[i] = *(const f32x4*)(bBase + (size_t)(i * 32) * redK + h * 32u);
    }
  };
  auto stage = [&](const f32x4* rA, const f32x4* rB) {
#pragma unroll
    for (int i = 0; i < 4; ++i) {
      bf16x4_t a, b;
#pragma unroll
      for (int j = 0; j < 4; ++j) {
        a[j] = (__bf16)rA[i][j];
        b[j] = (__bf16)rB[i][j];
      }
      *(bf16x4_t*)&As[(i * 32 + lRow) * BK + lCol] = a;
      *(bf16x4_t*)&Bs[(i * 32 + lRow) * BK + lCol] = b;
    }
  };

  f32x4 acc[4][4] = {};
  auto compute = [&]() {
    // A/B operand map: elem[m or n = lane&15][k = (lane>>4)*8 + j]
    bf16x8_t af[4], bfr[4];
    const int kOff = (lane >> 4) << 3;
    const int r16 = lane & 15;
#pragma unroll
    for (int mi = 0; mi < 4; ++mi)
      af[mi] = *(const bf16x8_t*)&As[((wm << 6) + (mi << 4) + r16) * BK + kOff];
#pragma unroll
    for (int ni = 0; ni < 4; ++ni)
      bfr[ni] = *(const bf16x8_t*)&Bs[((wn << 6) + (ni << 4) + r16) * BK + kOff];
#pragma unroll
    for (int mi = 0; mi < 4; ++mi)
#pragma unroll
      for (int ni = 0; ni < 4; ++ni)
        acc[mi][ni] = __builtin_amdgcn_mfma_f32_16x16x32_bf16(
            af[mi], bfr[ni], acc[mi][ni], 0, 0, 0);
  };

  // ---- K loop: ping-pong register buffers, numKb assumed even (K=8192)
  const int numKb = K / BK;
  f32x4 a0[4], b0[4], a1[4], b1[4];
  loadA(0, a0);
  loadB(0, b0);
  for (int kb = 0; kb < numKb; kb += 2) {
    if (kb + 1 < numKb) { loadA(kb + 1, a1); loadB(kb + 1, b1); }
    __syncthreads();   // prev iteration's ds_reads complete
    stage(a0, b0);     // waits vmcnt only for a0/b0
    __syncthreads();
    compute();
    if (kb + 2 < numKb) { loadA(kb + 2, a0); loadB(kb + 2, b0); }
    __syncthreads();
    stage(a1, b1);
    __syncthreads();
    compute();
  }

  // ---- epilogue: C/D map col(n)=lane&15, row(m)=(lane>>4)*4+reg
  const int mBase = mTile * BM + (wm << 6);
  const int nBase = nTile * BN + (wn << 6);
#pragma unroll
  for (int ni = 0; ni < 4; ++ni) {
    const int n = nBase + (ni << 4) + (lane & 15);
    const float bv = Bias[n];
#pragma unroll
    for (int mi = 0; mi < 4; ++mi) {
      const int m0 = mBase + (mi << 4) + ((lane >> 4) << 2);
#pragma unroll
      for (int r = 0; r < 4; ++r)
        Out[(size_t)(m0 + r) * N + n] = acc[mi][ni][r] + bv;
    }
  }
}

extern "C" void kernel_launch(void* const* d_in, const int* in_sizes, int n_in,
                              void* d_out, int out_size, void* d_ws, size_t ws_size,
                              hipStream_t stream) {
  const float* X = (const float*)d_in[0];
  const float* W = (const float*)d_in[1];
  const float* Bias = (const float*)d_in[2];
  const int* RN = (const int*)d_in[3];
  float* Out = (float*)d_out;

  const int N = in_sizes[2];             // 512
  const int M = out_size / N;            // 8192
  const int K = in_sizes[0] / M;         // 8192
  const int redK = in_sizes[1] / N;      // 1024
  const uint32_t numRedKb = (uint32_t)(redK / 32);  // 32

  const int mTiles = M / BM;             // 64
  const int nTiles = N / BN;             // 4
  dim3 grid(mTiles * nTiles), block(256);
  ssl_gemm<<<grid, block, 0, stream>>>(X, W, Bias, RN, Out,
                                       M, N, K, redK, numRedKb, mTiles);
}

// Round 3
// 504.066 us; speedup vs baseline: 1.0940x; 1.0940x over previous
//
#include <hip/hip_runtime.h>
#include <hip/hip_bf16.h>
#include <stdint.h>

// SSL hashed-sparse linear: out[M,N] = x[M,K] @ w_full[N,K]^T + bias
// w_full[n,k] = weight[n, h(n/32, k/32)*32 + k%32],
// h = ((kb*r0 + nb*r1 + r2) ^ r3) % num_red_kb   (uint32)
//
// fp32 in/out; compute in bf16 MFMA (threshold 0.165 allows it; r2 absmax 0.03).
// ROUND-3: split-K x4 -> grid 1024 = 4 blocks/CU = 16 waves/CU (was 1 block/CU,
// Occupancy 11.7% and ~2790 cyc/K-step of exposed HBM latency since
// __syncthreads drains vmcnt(0)). Other blocks now fill the barrier-drain
// stalls (m114 wave-overlap). Epilogue: unsafeAtomicAdd into Out, bias
// pre-seeded by init kernel. LDS rows padded to 40 bf16 (80 B) -> ds_write
// conflicts 4-way->2-way (free), ds_read_b128 2-way (free).

typedef __bf16 bf16x4_t __attribute__((ext_vector_type(4)));
typedef __bf16 bf16x8_t __attribute__((ext_vector_type(8)));
typedef float f32x4 __attribute__((ext_vector_type(4)));

#define BM 128
#define BN 128
#define BK 32
#define LDSK 40   // padded row stride (bf16 elems); 80 B, multiple of 16 B
#define KSPLIT 4

__global__ void init_out(float* __restrict__ Out, const float* __restrict__ Bias,
                         int N, int total4) {
  int i = blockIdx.x * blockDim.x + threadIdx.x;
  if (i < total4) {
    int idx = i << 2;
    int n = idx % N;                       // multiple of 4 since N%4==0
    *(f32x4*)(Out + idx) = *(const f32x4*)(Bias + n);
  }
}

__global__ __launch_bounds__(256, 1) void ssl_gemm(
    const float* __restrict__ X,       // [M,K]
    const float* __restrict__ W,       // [N,redK]
    const int* __restrict__ RN,        // [4]
    float* __restrict__ Out,           // [M,N], pre-seeded with bias
    int M, int N, int K, int redK, uint32_t numRedKb, int mTiles, int nTiles) {
  __shared__ __align__(16) __bf16 As[BM * LDSK];
  __shared__ __align__(16) __bf16 Bs[BN * LDSK];

  const uint32_t r0 = (uint32_t)RN[0], r1 = (uint32_t)RN[1];
  const uint32_t r2 = (uint32_t)RN[2], r3 = (uint32_t)RN[3];
  const uint32_t redMask = numRedKb - 1u;
  const bool pow2 = (numRedKb & (numRedKb - 1u)) == 0u;

  const int id = blockIdx.x;
  // id = m + mTiles*(n + nTiles*s); mTiles=64 (mult of 8) -> all blocks of an
  // m-tile share id%8 -> same XCD -> the 4 n-tile blocks of each (m,s) group
  // re-read the same A chunk through that XCD's L2.
  const int mTile = id % mTiles;
  const int rest = id / mTiles;
  const int nTile = rest % nTiles;
  const int kChunk = rest / nTiles;      // 0..KSPLIT-1

  const int tid = threadIdx.x;
  const int wave = tid >> 6;
  const int lane = tid & 63;
  const int wm = wave >> 1, wn = wave & 1;  // 2x2 wave grid, each 64x64

  // staging map: thread covers rows {i*32+lRow}, cols lCol..lCol+3
  const int lRow = tid >> 3;        // 0..31
  const int lCol = (tid & 7) << 2;  // 0,4,..,28
  const float* aBase = X + (size_t)(mTile * BM + lRow) * K + lCol;
  const float* bBase = W + (size_t)(nTile * BN + lRow) * redK + lCol;

  auto loadA = [&](int kb, f32x4* r) {
    const float* p = aBase + (size_t)kb * BK;
#pragma unroll
    for (int i = 0; i < 4; ++i)
      r[i] = *(const f32x4*)(p + (size_t)(i * 32) * K);
  };
  auto loadB = [&](int kb, f32x4* r) {
    const uint32_t kk = (uint32_t)kb * r0 + r2;
#pragma unroll
    for (int i = 0; i < 4; ++i) {
      const uint32_t nb = (uint32_t)(nTile * (BN / 32) + i);
      const uint32_t hv = (kk + nb * r1) ^ r3;
      const uint32_t h = pow2 ? (hv & redMask) : (hv % numRedKb);
      r[i] = *(const f32x4*)(bBase + (size_t)(i * 32) * redK + h * 32u);
    }
  };
  auto stage = [&](const f32x4* rA, const f32x4* rB) {
#pragma unroll
    for (int i = 0; i < 4; ++i) {
      bf16x4_t a, b;
#pragma unroll
      for (int j = 0; j < 4; ++j) {
        a[j] = (__bf16)rA[i][j];
        b[j] = (__bf16)rB[i][j];
      }
      *(bf16x4_t*)&As[(i * 32 + lRow) * LDSK + lCol] = a;
      *(bf16x4_t*)&Bs[(i * 32 + lRow) * LDSK + lCol] = b;
    }
  };

  f32x4 acc[4][4] = {};
  auto compute = [&]() {
    bf16x8_t af[4], bfr[4];
    const int kOff = (lane >> 4) << 3;   // 0 or 8 elems -> 0/16 B (aligned)
    const int r16 = lane & 15;
#pragma unroll
    for (int mi = 0; mi < 4; ++mi)
      af[mi] = *(const bf16x8_t*)&As[((wm << 6) + (mi << 4) + r16) * LDSK + kOff];
#pragma unroll
    for (int ni = 0; ni < 4; ++ni)
      bfr[ni] = *(const bf16x8_t*)&Bs[((wn << 6) + (ni << 4) + r16) * LDSK + kOff];
#pragma unroll
    for (int mi = 0; mi < 4; ++mi)
#pragma unroll
      for (int ni = 0; ni < 4; ++ni)
        acc[mi][ni] = __builtin_amdgcn_mfma_f32_16x16x32_bf16(
            af[mi], bfr[ni], acc[mi][ni], 0, 0, 0);
  };

  // K loop over this block's chunk (numKb/KSPLIT steps, even: 256/4=64)
  const int numKb = K / BK;
  const int kbN = numKb / KSPLIT;
  const int kb0 = kChunk * kbN;
  f32x4 a0[4], b0[4], a1[4], b1[4];
  loadA(kb0, a0);
  loadB(kb0, b0);
  for (int i = 0; i < kbN; i += 2) {
    if (i + 1 < kbN) { loadA(kb0 + i + 1, a1); loadB(kb0 + i + 1, b1); }
    __syncthreads();
    stage(a0, b0);
    __syncthreads();
    compute();
    if (i + 2 < kbN) { loadA(kb0 + i + 2, a0); loadB(kb0 + i + 2, b0); }
    __syncthreads();
    stage(a1, b1);
    __syncthreads();
    compute();
  }

  // epilogue: C/D map col(n)=lane&15, row(m)=(lane>>4)*4+reg; atomic accumulate
  const int mBase = mTile * BM + (wm << 6);
  const int nBase = nTile * BN + (wn << 6);
#pragma unroll
  for (int ni = 0; ni < 4; ++ni) {
    const int n = nBase + (ni << 4) + (lane & 15);
#pragma unroll
    for (int mi = 0; mi < 4; ++mi) {
      const int m0 = mBase + (mi << 4) + ((lane >> 4) << 2);
#pragma unroll
      for (int r = 0; r < 4; ++r)
        unsafeAtomicAdd(&Out[(size_t)(m0 + r) * N + n], acc[mi][ni][r]);
    }
  }
}

extern "C" void kernel_launch(void* const* d_in, const int* in_sizes, int n_in,
                              void* d_out, int out_size, void* d_ws, size_t ws_size,
                              hipStream_t stream) {
  const float* X = (const float*)d_in[0];
  const float* W = (const float*)d_in[1];
  const float* Bias = (const float*)d_in[2];
  const int* RN = (const int*)d_in[3];
  float* Out = (float*)d_out;

  const int N = in_sizes[2];             // 512
  const int M = out_size / N;            // 8192
  const int K = in_sizes[0] / M;         // 8192
  const int redK = in_sizes[1] / N;      // 1024
  const uint32_t numRedKb = (uint32_t)(redK / 32);  // 32

  const int total4 = out_size / 4;
  init_out<<<(total4 + 255) / 256, 256, 0, stream>>>(Out, Bias, N, total4);

  const int mTiles = M / BM;             // 64
  const int nTiles = N / BN;             // 4
  dim3 grid(mTiles * nTiles * KSPLIT), block(256);
  ssl_gemm<<<grid, block, 0, stream>>>(X, W, RN, Out,
                                       M, N, K, redK, numRedKb, mTiles, nTiles);
}